// Round 2
// baseline (870.968 us; speedup 1.0000x reference)
//
#include <hip/hip_runtime.h>

// F2FConv3d on MI355X.
// contrib = (x ⊗ bary) @ Wflat  as f16 MFMA (16x16x32), W = A-operand in registers.
// K ordering: p = kbasis*64 + i  (chunk c of 32: kbasis = c>>1, i = (c&1)*32 + [0,32)).
// Wave w owns output channels [w*16, w*16+16): A-frags = 18 x half8 = 72 VGPRs, loaded once.
// B-frag (per 16-texture group): lane's texture t = g*16 + (lane&15);
//   element j: x[t][(c&1)*32 + quad*8 + j] * bary[t][c>>1]   (quad = lane>>4).
// D layout (measured, m89): row = quad*4 + reg (channel), col = lane&15 (texture)
//   -> facet (4 consecutive textures) = shfl_xor 1,2 across lanes.

typedef _Float16 half8  __attribute__((ext_vector_type(8)));
typedef _Float16 h2     __attribute__((ext_vector_type(2)));
typedef __fp16   fp16x2 __attribute__((ext_vector_type(2)));
typedef float    f32x4  __attribute__((ext_vector_type(4)));
typedef float    f32x4u __attribute__((ext_vector_type(4), aligned(4)));

#define NGROUPS 100000   // 1.6M textures / 16 per group
#define FFACETS 400000
#define GRID1   1024

union HF { h2 h[4]; half8 v; };

static __device__ __forceinline__ h2 pkrtz(float a, float b) {
    fp16x2 r = __builtin_amdgcn_cvt_pkrtz(a, b);
    return __builtin_bit_cast(h2, r);
}

// ---- kernel 1: swizzle W (fp32 [64][64][9]) -> f16 fragment order in ws, zero stats
__global__ __launch_bounds__(256) void prep_kernel(const float* __restrict__ W,
                                                   _Float16* __restrict__ wswz,
                                                   float* __restrict__ stats) {
    int idx = blockIdx.x * 256 + threadIdx.x;
    if (idx < 36864) {
        int j    = idx & 7;
        int lane = (idx >> 3) & 63;
        int mt   = (idx >> 9) & 3;        // which wave (channel tile)
        int c    = idx >> 11;             // K chunk 0..17
        int o    = mt * 16 + (lane & 15);
        int i    = (c & 1) * 32 + ((lane >> 4) << 3) + j;
        int kb   = c >> 1;
        wswz[idx] = (_Float16)W[(o * 64 + i) * 9 + kb];
    }
    if (idx < 128) stats[idx] = 0.0f;
}

// ---- kernel 2: fused GEMM + facet mean + bias + ReLU + BN-stat accumulation
__global__ __launch_bounds__(256, 2) void pass1_kernel(
    const float* __restrict__ X, const float* __restrict__ BARY,
    const _Float16* __restrict__ WSWZ, const float* __restrict__ BIAS,
    const int* __restrict__ NTEX, float* __restrict__ OUT,
    float* __restrict__ stats) {

    __shared__ float sl_s[64];
    __shared__ float sl_s2[64];

    const int tid  = threadIdx.x;
    const int wave = tid >> 6;
    const int lane = tid & 63;
    const int col  = lane & 15;   // texture within group / MFMA column
    const int quad = lane >> 4;

    // A-operand: this wave's 16 output channels, all K. 72 VGPRs, resident whole kernel.
    half8 wf[18];
#pragma unroll
    for (int c = 0; c < 18; ++c)
        wf[c] = *(const half8*)(WSWZ + ((size_t)(c * 4 + wave) * 64 + lane) * 8);

    // bias for this lane's 4 channels: ch = wave*16 + quad*4 + r
    const f32x4 biasv = *(const f32x4*)(BIAS + wave * 16 + quad * 4);

    float sacc[4]  = {0.f, 0.f, 0.f, 0.f};
    float s2acc[4] = {0.f, 0.f, 0.f, 0.f};

    for (int g = blockIdx.x; g < NGROUPS; g += GRID1) {
        const int t = g * 16 + col;
        const float* xp = X + (size_t)t * 64 + quad * 8;
        f32x4 x0 = *(const f32x4*)(xp);
        f32x4 x1 = *(const f32x4*)(xp + 4);
        f32x4 x2 = *(const f32x4*)(xp + 32);
        f32x4 x3 = *(const f32x4*)(xp + 36);
        const float* bp = BARY + (size_t)t * 9;
        f32x4u b0 = *(const f32x4u*)(bp);
        f32x4u b1 = *(const f32x4u*)(bp + 4);
        float  b8 = bp[8];

        h2 xh[8];
        xh[0] = pkrtz(x0[0], x0[1]);
        xh[1] = pkrtz(x0[2], x0[3]);
        xh[2] = pkrtz(x1[0], x1[1]);
        xh[3] = pkrtz(x1[2], x1[3]);
        xh[4] = pkrtz(x2[0], x2[1]);
        xh[5] = pkrtz(x2[2], x2[3]);
        xh[6] = pkrtz(x3[0], x3[1]);
        xh[7] = pkrtz(x3[2], x3[3]);
        h2 bh[9];
        bh[0] = pkrtz(b0[0], b0[0]);
        bh[1] = pkrtz(b0[1], b0[1]);
        bh[2] = pkrtz(b0[2], b0[2]);
        bh[3] = pkrtz(b0[3], b0[3]);
        bh[4] = pkrtz(b1[0], b1[0]);
        bh[5] = pkrtz(b1[1], b1[1]);
        bh[6] = pkrtz(b1[2], b1[2]);
        bh[7] = pkrtz(b1[3], b1[3]);
        bh[8] = pkrtz(b8, b8);

        f32x4 acc = {0.f, 0.f, 0.f, 0.f};
#pragma unroll
        for (int c = 0; c < 18; ++c) {
            const int hh = (c & 1) * 4;
            const h2  bk = bh[c >> 1];
            HF bf;
            bf.h[0] = xh[hh + 0] * bk;
            bf.h[1] = xh[hh + 1] * bk;
            bf.h[2] = xh[hh + 2] * bk;
            bf.h[3] = xh[hh + 3] * bk;
            acc = __builtin_amdgcn_mfma_f32_16x16x32_f16(wf[c], bf.v, acc, 0, 0, 0);
        }

        // facet = 4 consecutive textures = 4 adjacent lanes (cols)
        const int f = g * 4 + (col >> 2);
        const float rc = 1.0f / (float)NTEX[f];
        f32x4 vv;
#pragma unroll
        for (int r = 0; r < 4; ++r) {
            float s = acc[r];
            s += __shfl_xor(s, 1);
            s += __shfl_xor(s, 2);
            s = s * rc + biasv[r];
            s = s > 0.f ? s : 0.f;
            vv[r] = s;
            sacc[r]  += s;         // every lane in the col-group holds same value:
            s2acc[r] += s * s;     // 4x overcount, corrected by 0.25 at the end
        }
        if ((col & 3) == 0)
            *(f32x4*)(OUT + (size_t)f * 64 + wave * 16 + quad * 4) = vv;
    }

    // reduce stats across the 16 cols (facet subsets); channels partitioned by (wave,quad,r)
#pragma unroll
    for (int r = 0; r < 4; ++r) {
        float s = sacc[r], s2 = s2acc[r];
        s  += __shfl_xor(s, 1);  s  += __shfl_xor(s, 2);
        s  += __shfl_xor(s, 4);  s  += __shfl_xor(s, 8);
        s2 += __shfl_xor(s2, 1); s2 += __shfl_xor(s2, 2);
        s2 += __shfl_xor(s2, 4); s2 += __shfl_xor(s2, 8);
        if (col == 0) {
            sl_s [wave * 16 + quad * 4 + r] = s  * 0.25f;
            sl_s2[wave * 16 + quad * 4 + r] = s2 * 0.25f;
        }
    }
    __syncthreads();
    if (tid < 64)        atomicAdd(&stats[tid],      sl_s [tid]);
    else if (tid < 128)  atomicAdd(&stats[tid],      sl_s2[tid - 64]);
}

// ---- kernel 3: in-place batch-norm normalize on OUT
__global__ __launch_bounds__(256) void pass3_kernel(float* __restrict__ OUT,
    const float* __restrict__ stats, const float* __restrict__ gamma,
    const float* __restrict__ beta) {
    const int tid = threadIdx.x;
    const size_t l = (size_t)blockIdx.x * 256 + tid;
    const int c0 = ((int)l & 15) * 4;     // grid*256 is a multiple of 16 -> constant per thread
    float mu[4], sc[4], be[4];
    const float invF = 1.0f / (float)FFACETS;
#pragma unroll
    for (int u = 0; u < 4; ++u) {
        int ch = c0 + u;
        float m  = stats[ch] * invF;
        float va = stats[64 + ch] * invF - m * m;
        mu[u] = m;
        sc[u] = rsqrtf(va + 1e-3f) * gamma[ch];
        be[u] = beta[ch];
    }
    const size_t n4 = (size_t)FFACETS * 16;
    for (size_t i = l; i < n4; i += (size_t)gridDim.x * 256) {
        f32x4 v = ((f32x4*)OUT)[i];
#pragma unroll
        for (int u = 0; u < 4; ++u)
            v[u] = (v[u] - mu[u]) * sc[u] + be[u];
        ((f32x4*)OUT)[i] = v;
    }
}

extern "C" void kernel_launch(void* const* d_in, const int* in_sizes, int n_in,
                              void* d_out, int out_size, void* d_ws, size_t ws_size,
                              hipStream_t stream) {
    const float* X     = (const float*)d_in[0];
    const float* BARY  = (const float*)d_in[1];
    const float* W     = (const float*)d_in[2];
    const float* BIAS  = (const float*)d_in[3];
    const float* GAMMA = (const float*)d_in[4];
    const float* BETA  = (const float*)d_in[5];
    const int*   NTEX  = (const int*)d_in[6];
    float* OUT = (float*)d_out;

    _Float16* wswz = (_Float16*)d_ws;                       // 73728 B
    float* stats   = (float*)((char*)d_ws + 73728);         // 128 floats

    prep_kernel<<<144, 256, 0, stream>>>(W, wswz, stats);
    pass1_kernel<<<GRID1, 256, 0, stream>>>(X, BARY, wswz, BIAS, NTEX, OUT, stats);
    pass3_kernel<<<2048, 256, 0, stream>>>(OUT, stats, GAMMA, BETA);
}